// Round 2
// baseline (913.688 us; speedup 1.0000x reference)
//
#include <hip/hip_runtime.h>
#include <cstdint>
#include <cstddef>

#define NN 100000   // nodes
#define NE 1600000  // edges
#define DD 128      // feature dim
#define NG 64       // graphs

__device__ __forceinline__ int clampi(int v, int hi) {
    // clamp to [0, hi-1] — defensive: garbage indices must not fault the GPU
    v = v < 0 ? 0 : v;
    return v >= hi ? hi - 1 : v;
}

// ---------------------------------------------------------------------------
// CSR build: histogram -> scan -> fill
// ---------------------------------------------------------------------------
__global__ void hist_kernel(const int* __restrict__ dst, int* __restrict__ cnt) {
    int e = blockIdx.x * 256 + threadIdx.x;
    if (e < NE) atomicAdd(&cnt[clampi(dst[e], NN)], 1);
}

// block scans a 1024 chunk (exclusive), writes chunk total to bsum
__global__ void scan1_kernel(int* __restrict__ data, int* __restrict__ bsum) {
    __shared__ int sh[256];
    int t = threadIdx.x;
    int i0 = blockIdx.x * 1024 + t * 4;
    int v[4]; int s = 0;
#pragma unroll
    for (int q = 0; q < 4; ++q) { int i = i0 + q; v[q] = (i < NN) ? data[i] : 0; s += v[q]; }
    sh[t] = s; __syncthreads();
    for (int d = 1; d < 256; d <<= 1) {
        int x = (t >= d) ? sh[t - d] : 0;
        __syncthreads();
        sh[t] += x;
        __syncthreads();
    }
    int run = sh[t] - s;               // exclusive prefix of this thread's chunk
    if (t == 255) bsum[blockIdx.x] = sh[255];
#pragma unroll
    for (int q = 0; q < 4; ++q) { int i = i0 + q; if (i < NN) { int val = v[q]; data[i] = run; run += val; } }
}

__global__ void scan2_kernel(int* __restrict__ bsum, int nb) {
    if (threadIdx.x == 0 && blockIdx.x == 0) {
        int run = 0;
        for (int b = 0; b < nb; ++b) { int x = bsum[b]; bsum[b] = run; run += x; }
    }
}

__global__ void scan3_kernel(int* __restrict__ row_ptr, const int* __restrict__ bsum,
                             int* __restrict__ cur) {
    int i = blockIdx.x * 256 + threadIdx.x;
    if (i < NN) { int v = row_ptr[i] + bsum[i >> 10]; row_ptr[i] = v; cur[i] = v; }
    if (i == 0) row_ptr[NN] = NE;
}

__global__ void fill_kernel(const int* __restrict__ src, const int* __restrict__ dst,
                            int* __restrict__ cur, int* __restrict__ csr) {
    int e = blockIdx.x * 256 + threadIdx.x;
    if (e < NE) {
        int p = atomicAdd(&cur[clampi(dst[e], NN)], 1);
        if (p >= 0 && p < NE) csr[p] = clampi(src[e], NN);
    }
}

// ---------------------------------------------------------------------------
// Pull aggregation: one wave per dst node, mean of h[src] rows (f32, no atomics)
// ---------------------------------------------------------------------------
__global__ __launch_bounds__(256) void pull_kernel(
    const float* __restrict__ h, const int* __restrict__ row_ptr,
    const int* __restrict__ csr, float* __restrict__ agg) {
    int w = threadIdx.x >> 6, lane = threadIdx.x & 63;
    int n = blockIdx.x * 4 + w;
    if (n >= NN) return;
    int s0 = row_ptr[n], s1 = row_ptr[n + 1];
    int len = s1 - s0;
    float inv = 1.0f / (float)(len > 0 ? len : 1);
    float ax = 0.f, ay = 0.f;
    int j = s0;
    for (; j + 4 <= s1; j += 4) {
        int i0 = csr[j], i1 = csr[j + 1], i2 = csr[j + 2], i3 = csr[j + 3];
        const float2 v0 = *(const float2*)(h + (size_t)i0 * DD + lane * 2);
        const float2 v1 = *(const float2*)(h + (size_t)i1 * DD + lane * 2);
        const float2 v2 = *(const float2*)(h + (size_t)i2 * DD + lane * 2);
        const float2 v3 = *(const float2*)(h + (size_t)i3 * DD + lane * 2);
        ax += (v0.x + v1.x) + (v2.x + v3.x);
        ay += (v0.y + v1.y) + (v2.y + v3.y);
    }
    for (; j < s1; ++j) {
        int i0 = csr[j];
        const float2 v0 = *(const float2*)(h + (size_t)i0 * DD + lane * 2);
        ax += v0.x; ay += v0.y;
    }
    float2 r; r.x = ax * inv; r.y = ay * inv;
    *(float2*)(agg + (size_t)n * DD + lane * 2) = r;
}

// ---------------------------------------------------------------------------
// Fused SAGE layer: out = relu(normalize(agg@Wr^T + h@Wl^T + bl + [deg>0]*br))
// Tiled f32 GEMM: BM=64 nodes, N=128 outs, K=256 (h | agg), 256 thr, 8x4 reg tile
// ---------------------------------------------------------------------------
__global__ __launch_bounds__(256) void sage_layer(
    const float* __restrict__ hIn, const float* __restrict__ agg,
    const float* __restrict__ Wl, const float* __restrict__ Wr,
    const float* __restrict__ bl, const float* __restrict__ br,
    const int* __restrict__ row_ptr, float* __restrict__ hOut) {
    __shared__ float As[32][68];    // [k][node], padded
    __shared__ float Bs[32][132];   // [k][o],   padded
    const int tid = threadIdx.x;
    const int tx = tid & 31, ty = tid >> 5;
    const int n0 = blockIdx.x * 64;

    float acc[8][4];
#pragma unroll
    for (int r = 0; r < 8; ++r)
#pragma unroll
        for (int c = 0; c < 4; ++c) acc[r][c] = 0.f;

    for (int kt = 0; kt < 8; ++kt) {
        const float* A = (kt < 4) ? hIn : agg;
        const float* W = (kt < 4) ? Wl : Wr;
        const int k0 = (kt & 3) * 32;
        __syncthreads();
        {
            const int ks = (tid & 7) * 4;
            const int rl = tid >> 3;  // 0..31
#pragma unroll
            for (int jj = 0; jj < 2; ++jj) {
                int node = rl + jj * 32;
                int rg = n0 + node; rg = rg < NN ? rg : NN - 1;
                const float4 v = *(const float4*)(A + (size_t)rg * DD + k0 + ks);
                As[ks + 0][node] = v.x; As[ks + 1][node] = v.y;
                As[ks + 2][node] = v.z; As[ks + 3][node] = v.w;
            }
#pragma unroll
            for (int jj = 0; jj < 4; ++jj) {
                int o = rl + jj * 32;
                const float4 v = *(const float4*)(W + (size_t)o * DD + k0 + ks);
                Bs[ks + 0][o] = v.x; Bs[ks + 1][o] = v.y;
                Bs[ks + 2][o] = v.z; Bs[ks + 3][o] = v.w;
            }
        }
        __syncthreads();
#pragma unroll 8
        for (int kk = 0; kk < 32; ++kk) {
            const float4 bv = *(const float4*)(&Bs[kk][tx * 4]);
            const float4 a0 = *(const float4*)(&As[kk][ty * 8]);
            const float4 a1 = *(const float4*)(&As[kk][ty * 8 + 4]);
            const float ar[8] = {a0.x, a0.y, a0.z, a0.w, a1.x, a1.y, a1.z, a1.w};
            const float bc_[4] = {bv.x, bv.y, bv.z, bv.w};
#pragma unroll
            for (int r = 0; r < 8; ++r)
#pragma unroll
                for (int c = 0; c < 4; ++c) acc[r][c] = fmaf(ar[r], bc_[c], acc[r][c]);
        }
    }

    // epilogue: bias, row L2-normalize (over 32 tx lanes), relu, store
    const float4 blv = *(const float4*)(bl + tx * 4);
    const float4 brv = *(const float4*)(br + tx * 4);
#pragma unroll
    for (int r = 0; r < 8; ++r) {
        int node = n0 + ty * 8 + r;
        bool valid = node < NN;
        int nd = valid ? node : 0;
        int degp = row_ptr[nd + 1] - row_ptr[nd];
        float bf = degp > 0 ? 1.f : 0.f;
        float o0 = acc[r][0] + blv.x + bf * brv.x;
        float o1 = acc[r][1] + blv.y + bf * brv.y;
        float o2 = acc[r][2] + blv.z + bf * brv.z;
        float o3 = acc[r][3] + blv.w + bf * brv.w;
        float ss = o0 * o0 + o1 * o1 + o2 * o2 + o3 * o3;
        ss += __shfl_xor(ss, 1);  ss += __shfl_xor(ss, 2);
        ss += __shfl_xor(ss, 4);  ss += __shfl_xor(ss, 8);
        ss += __shfl_xor(ss, 16);
        float nrm = fmaxf(sqrtf(ss), 1e-12f);
        float inv = 1.0f / nrm;
        float4 res;
        res.x = fmaxf(o0, 0.f) * inv; res.y = fmaxf(o1, 0.f) * inv;
        res.z = fmaxf(o2, 0.f) * inv; res.w = fmaxf(o3, 0.f) * inv;
        if (valid) *(float4*)(hOut + (size_t)node * DD + tx * 4) = res;
    }
}

// ---------------------------------------------------------------------------
// Pool: segment-mean of h3 by (sorted) batch -> pooled[64][128], cnt[64]
// ---------------------------------------------------------------------------
__global__ __launch_bounds__(256) void pool_kernel(
    const float* __restrict__ h, const int* __restrict__ batch,
    float* __restrict__ pooled, float* __restrict__ cnt) {
    int hw = (blockIdx.x * blockDim.x + threadIdx.x) >> 5;
    int lane = threadIdx.x & 31;
    int total_hw = (gridDim.x * blockDim.x) >> 5;
    int chunk = (NN + total_hw - 1) / total_hw;
    int nbeg = hw * chunk;
    int nend = nbeg + chunk; if (nend > NN) nend = NN;
    if (nbeg >= nend) return;
    float ax = 0.f, ay = 0.f, az = 0.f, aw = 0.f;
    int curg = clampi(batch[nbeg], NG);
    int run = 0;
    for (int n = nbeg; n < nend; ++n) {
        int g = clampi(batch[n], NG);
        if (g != curg) {
            atomicAdd(&pooled[curg * DD + lane * 4 + 0], ax);
            atomicAdd(&pooled[curg * DD + lane * 4 + 1], ay);
            atomicAdd(&pooled[curg * DD + lane * 4 + 2], az);
            atomicAdd(&pooled[curg * DD + lane * 4 + 3], aw);
            if (lane == 0) atomicAdd(&cnt[curg], (float)run);
            ax = ay = az = aw = 0.f; run = 0; curg = g;
        }
        const float4 v = *(const float4*)(h + (size_t)n * DD + lane * 4);
        ax += v.x; ay += v.y; az += v.z; aw += v.w; ++run;
    }
    atomicAdd(&pooled[curg * DD + lane * 4 + 0], ax);
    atomicAdd(&pooled[curg * DD + lane * 4 + 1], ay);
    atomicAdd(&pooled[curg * DD + lane * 4 + 2], az);
    atomicAdd(&pooled[curg * DD + lane * 4 + 3], aw);
    if (lane == 0) atomicAdd(&cnt[curg], (float)run);
}

// ---------------------------------------------------------------------------
// Fold MLP: Wc = W2 @ W1 (16x128), bc = W2 @ b1 + b2
// ---------------------------------------------------------------------------
__global__ void mlpfold_kernel(const float* __restrict__ W1, const float* __restrict__ b1,
                               const float* __restrict__ W2, const float* __restrict__ b2,
                               float* __restrict__ Wc, float* __restrict__ bc) {
    int t = blockIdx.x * 256 + threadIdx.x;
    if (t >= 16 * 128) return;
    int o = t >> 7, k = t & 127;
    float s = 0.f;
    for (int j = 0; j < 128; ++j) s = fmaf(W2[o * 128 + j], W1[j * 128 + k], s);
    Wc[o * 128 + k] = s;
    if (k == 0) {
        float sb = 0.f;
        for (int j = 0; j < 128; ++j) sb = fmaf(W2[o * 128 + j], b1[j], sb);
        bc[o] = sb + b2[o];
    }
}

// ---------------------------------------------------------------------------
// Final: mean -> micro GEMM [64][128]@[128][16] -> log_softmax -> d_out
// ---------------------------------------------------------------------------
__global__ void final_kernel(const float* __restrict__ pooled, const float* __restrict__ cnt,
                             const float* __restrict__ Wc, const float* __restrict__ bc,
                             float* __restrict__ out) {
    int t = threadIdx.x;          // 1024 = 64 graphs x 16 outs
    int g = t >> 4, o = t & 15;
    float invc = 1.0f / fmaxf(cnt[g], 1.0f);
    float z = bc[o];
    for (int k = 0; k < 128; ++k) z = fmaf(pooled[g * DD + k] * invc, Wc[o * 128 + k], z);
    float m = z;
    m = fmaxf(m, __shfl_xor(m, 1)); m = fmaxf(m, __shfl_xor(m, 2));
    m = fmaxf(m, __shfl_xor(m, 4)); m = fmaxf(m, __shfl_xor(m, 8));
    float e = expf(z - m);
    float s = e;
    s += __shfl_xor(s, 1); s += __shfl_xor(s, 2);
    s += __shfl_xor(s, 4); s += __shfl_xor(s, 8);
    out[g * 16 + o] = z - m - logf(s);
}

__global__ void zero_out_kernel(float* __restrict__ out, int n) {
    int i = blockIdx.x * 256 + threadIdx.x;
    if (i < n) out[i] = 0.f;
}

// ---------------------------------------------------------------------------
extern "C" void kernel_launch(void* const* d_in, const int* in_sizes, int n_in,
                              void* d_out, int out_size, void* d_ws, size_t ws_size,
                              hipStream_t stream) {
    const float* x  = (const float*)d_in[0];
    const int*   ei = (const int*)d_in[1];
    const int* batch = (const int*)d_in[2];
    const float* Wl = (const float*)d_in[3];
    const float* bl = (const float*)d_in[4];
    const float* Wr = (const float*)d_in[5];
    const float* br = (const float*)d_in[6];
    const float* W1 = (const float*)d_in[7];
    const float* b1 = (const float*)d_in[8];
    const float* W2 = (const float*)d_in[9];
    const float* b2 = (const float*)d_in[10];
    float* out = (float*)d_out;

    const int* src = ei;          // edge_index[0]
    const int* dst = ei + NE;     // edge_index[1]

    // workspace layout (~161 MB) — guard against undersized ws
    char* ws = (char*)d_ws;
    size_t off = 0;
    auto alloc = [&](size_t bytes) -> void* {
        void* p = ws + off; off += (bytes + 255) & ~(size_t)255; return p;
    };
    float* hA     = (float*)alloc((size_t)NN * DD * 4);
    float* hB     = (float*)alloc((size_t)NN * DD * 4);
    float* agg    = (float*)alloc((size_t)NN * DD * 4);
    int* row_ptr  = (int*)alloc((size_t)(NN + 1) * 4);
    int* cur      = (int*)alloc((size_t)NN * 4);
    int* csr      = (int*)alloc((size_t)NE * 4);
    int* bsum     = (int*)alloc(512 * 4);
    float* pooled = (float*)alloc(NG * DD * 4);
    float* cnt    = (float*)alloc(NG * 4);
    float* Wc     = (float*)alloc(16 * DD * 4);
    float* bc     = (float*)alloc(16 * 4);

    if (off > ws_size) {
        // workspace too small: fail visibly (wrong output) instead of faulting
        zero_out_kernel<<<(out_size + 255) / 256, 256, 0, stream>>>(out, out_size);
        return;
    }

    // CSR build
    hipMemsetAsync(row_ptr, 0, (size_t)(NN + 1) * 4, stream);
    hist_kernel<<<(NE + 255) / 256, 256, 0, stream>>>(dst, row_ptr);
    int nblk = (NN + 1023) / 1024;  // 98
    scan1_kernel<<<nblk, 256, 0, stream>>>(row_ptr, bsum);
    scan2_kernel<<<1, 64, 0, stream>>>(bsum, nblk);
    scan3_kernel<<<(NN + 255) / 256, 256, 0, stream>>>(row_ptr, bsum, cur);
    fill_kernel<<<(NE + 255) / 256, 256, 0, stream>>>(src, dst, cur, csr);

    // 3 SAGE layers
    const float* hin = x;
    float* bufs[2] = {hA, hB};
    for (int l = 0; l < 3; ++l) {
        float* hout = bufs[l & 1];
        pull_kernel<<<(NN + 3) / 4, 256, 0, stream>>>(hin, row_ptr, csr, agg);
        sage_layer<<<(NN + 63) / 64, 256, 0, stream>>>(
            hin, agg, Wl + (size_t)l * 128 * 128, Wr + (size_t)l * 128 * 128,
            bl + (size_t)l * 128, br + (size_t)l * 128, row_ptr, hout);
        hin = hout;
    }

    // pooled mean + folded MLP + log_softmax
    hipMemsetAsync(pooled, 0, (size_t)NG * DD * 4, stream);
    hipMemsetAsync(cnt, 0, (size_t)NG * 4, stream);
    pool_kernel<<<256, 256, 0, stream>>>(hin, batch, pooled, cnt);
    mlpfold_kernel<<<8, 256, 0, stream>>>(W1, b1, W2, b2, Wc, bc);
    final_kernel<<<1, 1024, 0, stream>>>(pooled, cnt, Wc, bc, out);
}

// Round 3
// 641.392 us; speedup vs baseline: 1.4245x; 1.4245x over previous
//
#include <hip/hip_runtime.h>
#include <cstdint>
#include <cstddef>

#define NN 100000   // nodes
#define NE 1600000  // edges
#define DD 128      // feature dim
#define NG 64       // graphs

using bf16x8 = __attribute__((ext_vector_type(8))) short;
using f32x4  = __attribute__((ext_vector_type(4))) float;

__device__ __forceinline__ int clampi(int v, int hi) {
    v = v < 0 ? 0 : v;
    return v >= hi ? hi - 1 : v;
}
__device__ __forceinline__ unsigned short f2bf(float f) {
    unsigned int u = __float_as_uint(f);
    u += 0x7fffu + ((u >> 16) & 1u);   // RNE
    return (unsigned short)(u >> 16);
}
__device__ __forceinline__ float bf2f(unsigned short s) {
    return __uint_as_float(((unsigned int)s) << 16);
}

// ---------------------------------------------------------------------------
// CSR build: histogram -> scan -> fill
// ---------------------------------------------------------------------------
__global__ void hist_kernel(const int* __restrict__ dst, int* __restrict__ cnt) {
    int e = blockIdx.x * 256 + threadIdx.x;
    if (e < NE) atomicAdd(&cnt[clampi(dst[e], NN)], 1);
}

__global__ void scan1_kernel(int* __restrict__ data, int* __restrict__ bsum) {
    __shared__ int sh[256];
    int t = threadIdx.x;
    int i0 = blockIdx.x * 1024 + t * 4;
    int v[4]; int s = 0;
#pragma unroll
    for (int q = 0; q < 4; ++q) { int i = i0 + q; v[q] = (i < NN) ? data[i] : 0; s += v[q]; }
    sh[t] = s; __syncthreads();
    for (int d = 1; d < 256; d <<= 1) {
        int x = (t >= d) ? sh[t - d] : 0;
        __syncthreads();
        sh[t] += x;
        __syncthreads();
    }
    int run = sh[t] - s;
    if (t == 255) bsum[blockIdx.x] = sh[255];
#pragma unroll
    for (int q = 0; q < 4; ++q) { int i = i0 + q; if (i < NN) { int val = v[q]; data[i] = run; run += val; } }
}

__global__ void scan2_kernel(int* __restrict__ bsum, int nb) {
    if (threadIdx.x == 0 && blockIdx.x == 0) {
        int run = 0;
        for (int b = 0; b < nb; ++b) { int x = bsum[b]; bsum[b] = run; run += x; }
    }
}

__global__ void scan3_kernel(int* __restrict__ row_ptr, const int* __restrict__ bsum,
                             int* __restrict__ cur) {
    int i = blockIdx.x * 256 + threadIdx.x;
    if (i < NN) { int v = row_ptr[i] + bsum[i >> 10]; row_ptr[i] = v; cur[i] = v; }
    if (i == 0) row_ptr[NN] = NE;
}

__global__ void fill_kernel(const int* __restrict__ src, const int* __restrict__ dst,
                            int* __restrict__ cur, int* __restrict__ csr) {
    int e = blockIdx.x * 256 + threadIdx.x;
    if (e < NE) {
        int p = atomicAdd(&cur[clampi(dst[e], NN)], 1);
        if (p >= 0 && p < NE) csr[p] = clampi(src[e], NN);
    }
}

// ---------------------------------------------------------------------------
// Convert kernels: x f32 -> bf16; weights -> concatenated bf16 [l][o][256]
// ---------------------------------------------------------------------------
__global__ void cvt_x_kernel(const float* __restrict__ x, unsigned short* __restrict__ xb) {
    int i = blockIdx.x * 256 + threadIdx.x;     // over NN*DD/4
    if (i >= NN * DD / 4) return;
    const float4 v = ((const float4*)x)[i];
    ushort4 r;
    r.x = f2bf(v.x); r.y = f2bf(v.y); r.z = f2bf(v.z); r.w = f2bf(v.w);
    ((ushort4*)xb)[i] = r;
}

__global__ void cvt_w_kernel(const float* __restrict__ Wl, const float* __restrict__ Wr,
                             unsigned short* __restrict__ Wcat) {
    int t = blockIdx.x * 256 + threadIdx.x;     // 3*128*256
    if (t >= 3 * 128 * 256) return;
    int l = t >> 15;            // /(128*256)
    int rem = t & 32767;
    int o = rem >> 8, k = rem & 255;
    float v = (k < 128) ? Wl[(size_t)l * 16384 + o * 128 + k]
                        : Wr[(size_t)l * 16384 + o * 128 + (k - 128)];
    Wcat[t] = f2bf(v);
}

// ---------------------------------------------------------------------------
// Pull aggregation (bf16): one wave per dst node, mean of h[src] rows
// ---------------------------------------------------------------------------
__global__ __launch_bounds__(256) void pull_bf16(
    const unsigned short* __restrict__ h, const int* __restrict__ row_ptr,
    const int* __restrict__ csr, unsigned short* __restrict__ agg) {
    int w = threadIdx.x >> 6, lane = threadIdx.x & 63;
    int n = blockIdx.x * 4 + w;
    if (n >= NN) return;
    int s0 = row_ptr[n], s1 = row_ptr[n + 1];
    int len = s1 - s0;
    float inv = 1.0f / (float)(len > 0 ? len : 1);
    float ax = 0.f, ay = 0.f;
    int j = s0;
    for (; j + 4 <= s1; j += 4) {
        int i0 = csr[j], i1 = csr[j + 1], i2 = csr[j + 2], i3 = csr[j + 3];
        unsigned int v0 = *(const unsigned int*)(h + (size_t)i0 * DD + lane * 2);
        unsigned int v1 = *(const unsigned int*)(h + (size_t)i1 * DD + lane * 2);
        unsigned int v2 = *(const unsigned int*)(h + (size_t)i2 * DD + lane * 2);
        unsigned int v3 = *(const unsigned int*)(h + (size_t)i3 * DD + lane * 2);
        ax += bf2f((unsigned short)v0) + bf2f((unsigned short)v1)
            + bf2f((unsigned short)v2) + bf2f((unsigned short)v3);
        ay += bf2f((unsigned short)(v0 >> 16)) + bf2f((unsigned short)(v1 >> 16))
            + bf2f((unsigned short)(v2 >> 16)) + bf2f((unsigned short)(v3 >> 16));
    }
    for (; j < s1; ++j) {
        unsigned int v0 = *(const unsigned int*)(h + (size_t)csr[j] * DD + lane * 2);
        ax += bf2f((unsigned short)v0);
        ay += bf2f((unsigned short)(v0 >> 16));
    }
    unsigned int packed = (unsigned int)f2bf(ax * inv) | ((unsigned int)f2bf(ay * inv) << 16);
    *(unsigned int*)(agg + (size_t)n * DD + lane * 2) = packed;
}

// ---------------------------------------------------------------------------
// Fused SAGE layer (MFMA bf16):
// out = relu(normalize(h@Wl^T + agg@Wr^T + bl + [deg>0]*br)) -> bf16
// Block: 256 thr = 4 waves (2 wm x 2 wn). BM=64 rows, BN=128 (full N), K=256.
// mfma_f32_16x16x32_bf16, M_rep=2, N_rep=4 per wave.
// ---------------------------------------------------------------------------
__global__ __launch_bounds__(256) void sage_mfma(
    const unsigned short* __restrict__ h, const unsigned short* __restrict__ agg,
    const unsigned short* __restrict__ Wcat, const float* __restrict__ bl,
    const float* __restrict__ br, const int* __restrict__ row_ptr,
    unsigned short* __restrict__ hOut) {
    __shared__ float ssh[2][64];
    const int tid = threadIdx.x;
    const int l = tid & 63;
    const int w = tid >> 6;
    const int wm = w & 1, wn = w >> 1;
    const int l15 = l & 15, lg = l >> 4;
    const int n0 = blockIdx.x * 64;

    f32x4 acc[2][4];
#pragma unroll
    for (int m = 0; m < 2; ++m)
#pragma unroll
        for (int n = 0; n < 4; ++n) acc[m][n] = (f32x4){0.f, 0.f, 0.f, 0.f};

    int nodeA[2];
#pragma unroll
    for (int m = 0; m < 2; ++m) {
        int r = n0 + wm * 32 + m * 16 + l15;
        nodeA[m] = r < NN ? r : NN - 1;
    }

#pragma unroll
    for (int ks = 0; ks < 8; ++ks) {
        const unsigned short* Abase = (ks < 4) ? h : agg;
        const int kk = (ks & 3) * 32 + lg * 8;
        const int kw = ks * 32 + lg * 8;
        bf16x8 a[2], b[4];
#pragma unroll
        for (int m = 0; m < 2; ++m)
            a[m] = *(const bf16x8*)(Abase + (size_t)nodeA[m] * DD + kk);
#pragma unroll
        for (int n = 0; n < 4; ++n) {
            int o = wn * 64 + n * 16 + l15;
            b[n] = *(const bf16x8*)(Wcat + o * 256 + kw);
        }
#pragma unroll
        for (int m = 0; m < 2; ++m)
#pragma unroll
            for (int n = 0; n < 4; ++n)
                acc[m][n] = __builtin_amdgcn_mfma_f32_16x16x32_bf16(a[m], b[n], acc[m][n], 0, 0, 0);
    }

    // epilogue: bias, cross-wave row L2-norm, relu, bf16 store
    float blv[4], brv[4];
#pragma unroll
    for (int n = 0; n < 4; ++n) {
        int o = wn * 64 + n * 16 + l15;
        blv[n] = bl[o]; brv[n] = br[o];
    }

    float outv[2][4][4];   // [mrep][nrep][reg]
#pragma unroll
    for (int m = 0; m < 2; ++m) {
#pragma unroll
        for (int r = 0; r < 4; ++r) {
            int row_local = wm * 32 + m * 16 + lg * 4 + r;
            int node = n0 + row_local;
            int nd = node < NN ? node : 0;
            float bf = (row_ptr[nd + 1] - row_ptr[nd]) > 0 ? 1.f : 0.f;
            float s = 0.f;
#pragma unroll
            for (int n = 0; n < 4; ++n) {
                float v = acc[m][n][r] + blv[n] + bf * brv[n];
                outv[m][n][r] = v;
                s = fmaf(v, v, s);
            }
            s += __shfl_xor(s, 1); s += __shfl_xor(s, 2);
            s += __shfl_xor(s, 4); s += __shfl_xor(s, 8);
            if (l15 == 0) ssh[wn][row_local] = s;
        }
    }
    __syncthreads();
#pragma unroll
    for (int m = 0; m < 2; ++m) {
#pragma unroll
        for (int r = 0; r < 4; ++r) {
            int row_local = wm * 32 + m * 16 + lg * 4 + r;
            int node = n0 + row_local;
            float tot = ssh[0][row_local] + ssh[1][row_local];
            float inv = 1.0f / fmaxf(sqrtf(tot), 1e-12f);
            if (node < NN) {
#pragma unroll
                for (int n = 0; n < 4; ++n) {
                    int o = wn * 64 + n * 16 + l15;
                    float v = fmaxf(outv[m][n][r], 0.f) * inv;
                    hOut[(size_t)node * DD + o] = f2bf(v);
                }
            }
        }
    }
}

// ---------------------------------------------------------------------------
// Pool: segment-mean of h3 (bf16) by sorted batch -> pooled[64][128], cnt[64]
// ---------------------------------------------------------------------------
__global__ __launch_bounds__(256) void pool_bf16(
    const unsigned short* __restrict__ h, const int* __restrict__ batch,
    float* __restrict__ pooled, float* __restrict__ cnt) {
    int hw = (blockIdx.x * blockDim.x + threadIdx.x) >> 5;
    int lane = threadIdx.x & 31;
    int total_hw = (gridDim.x * blockDim.x) >> 5;
    int chunk = (NN + total_hw - 1) / total_hw;
    int nbeg = hw * chunk;
    int nend = nbeg + chunk; if (nend > NN) nend = NN;
    if (nbeg >= nend) return;
    float ax = 0.f, ay = 0.f, az = 0.f, aw = 0.f;
    int curg = clampi(batch[nbeg], NG);
    int run = 0;
    for (int n = nbeg; n < nend; ++n) {
        int g = clampi(batch[n], NG);
        if (g != curg) {
            atomicAdd(&pooled[curg * DD + lane * 4 + 0], ax);
            atomicAdd(&pooled[curg * DD + lane * 4 + 1], ay);
            atomicAdd(&pooled[curg * DD + lane * 4 + 2], az);
            atomicAdd(&pooled[curg * DD + lane * 4 + 3], aw);
            if (lane == 0) atomicAdd(&cnt[curg], (float)run);
            ax = ay = az = aw = 0.f; run = 0; curg = g;
        }
        const ushort4 v = *(const ushort4*)(h + (size_t)n * DD + lane * 4);
        ax += bf2f(v.x); ay += bf2f(v.y); az += bf2f(v.z); aw += bf2f(v.w);
        ++run;
    }
    atomicAdd(&pooled[curg * DD + lane * 4 + 0], ax);
    atomicAdd(&pooled[curg * DD + lane * 4 + 1], ay);
    atomicAdd(&pooled[curg * DD + lane * 4 + 2], az);
    atomicAdd(&pooled[curg * DD + lane * 4 + 3], aw);
    if (lane == 0) atomicAdd(&cnt[curg], (float)run);
}

// ---------------------------------------------------------------------------
// Fold MLP: Wc = W2 @ W1 (16x128), bc = W2 @ b1 + b2
// ---------------------------------------------------------------------------
__global__ void mlpfold_kernel(const float* __restrict__ W1, const float* __restrict__ b1,
                               const float* __restrict__ W2, const float* __restrict__ b2,
                               float* __restrict__ Wc, float* __restrict__ bc) {
    int t = blockIdx.x * 256 + threadIdx.x;
    if (t >= 16 * 128) return;
    int o = t >> 7, k = t & 127;
    float s = 0.f;
    for (int j = 0; j < 128; ++j) s = fmaf(W2[o * 128 + j], W1[j * 128 + k], s);
    Wc[o * 128 + k] = s;
    if (k == 0) {
        float sb = 0.f;
        for (int j = 0; j < 128; ++j) sb = fmaf(W2[o * 128 + j], b1[j], sb);
        bc[o] = sb + b2[o];
    }
}

// ---------------------------------------------------------------------------
// Final: mean -> micro GEMM [64][128]@[128][16] -> log_softmax -> d_out
// ---------------------------------------------------------------------------
__global__ void final_kernel(const float* __restrict__ pooled, const float* __restrict__ cnt,
                             const float* __restrict__ Wc, const float* __restrict__ bc,
                             float* __restrict__ out) {
    int t = threadIdx.x;          // 1024 = 64 graphs x 16 outs
    int g = t >> 4, o = t & 15;
    float invc = 1.0f / fmaxf(cnt[g], 1.0f);
    float z = bc[o];
    for (int k = 0; k < 128; ++k) z = fmaf(pooled[g * DD + k] * invc, Wc[o * 128 + k], z);
    float m = z;
    m = fmaxf(m, __shfl_xor(m, 1)); m = fmaxf(m, __shfl_xor(m, 2));
    m = fmaxf(m, __shfl_xor(m, 4)); m = fmaxf(m, __shfl_xor(m, 8));
    float e = expf(z - m);
    float s = e;
    s += __shfl_xor(s, 1); s += __shfl_xor(s, 2);
    s += __shfl_xor(s, 4); s += __shfl_xor(s, 8);
    out[g * 16 + o] = z - m - logf(s);
}

__global__ void zero_out_kernel(float* __restrict__ out, int n) {
    int i = blockIdx.x * 256 + threadIdx.x;
    if (i < n) out[i] = 0.f;
}

// ---------------------------------------------------------------------------
extern "C" void kernel_launch(void* const* d_in, const int* in_sizes, int n_in,
                              void* d_out, int out_size, void* d_ws, size_t ws_size,
                              hipStream_t stream) {
    const float* x  = (const float*)d_in[0];
    const int*   ei = (const int*)d_in[1];
    const int* batch = (const int*)d_in[2];
    const float* Wl = (const float*)d_in[3];
    const float* bl = (const float*)d_in[4];
    const float* Wr = (const float*)d_in[5];
    const float* br = (const float*)d_in[6];
    const float* W1 = (const float*)d_in[7];
    const float* b1 = (const float*)d_in[8];
    const float* W2 = (const float*)d_in[9];
    const float* b2 = (const float*)d_in[10];
    float* out = (float*)d_out;

    const int* src = ei;          // edge_index[0]
    const int* dst = ei + NE;     // edge_index[1]

    // workspace layout — guard against undersized ws
    char* ws = (char*)d_ws;
    size_t off = 0;
    auto alloc = [&](size_t bytes) -> void* {
        void* p = ws + off; off += (bytes + 255) & ~(size_t)255; return p;
    };
    unsigned short* xb   = (unsigned short*)alloc((size_t)NN * DD * 2);
    unsigned short* hA   = (unsigned short*)alloc((size_t)NN * DD * 2);
    unsigned short* hB   = (unsigned short*)alloc((size_t)NN * DD * 2);
    unsigned short* aggb = (unsigned short*)alloc((size_t)NN * DD * 2);
    unsigned short* Wcat = (unsigned short*)alloc((size_t)3 * 128 * 256 * 2);
    int* row_ptr  = (int*)alloc((size_t)(NN + 1) * 4);
    int* cur      = (int*)alloc((size_t)NN * 4);
    int* csr      = (int*)alloc((size_t)NE * 4);
    int* bsum     = (int*)alloc(512 * 4);
    float* pooled = (float*)alloc(NG * DD * 4);
    float* cnt    = (float*)alloc(NG * 4);
    float* Wc     = (float*)alloc(16 * DD * 4);
    float* bc     = (float*)alloc(16 * 4);

    if (off > ws_size) {
        zero_out_kernel<<<(out_size + 255) / 256, 256, 0, stream>>>(out, out_size);
        return;
    }

    // conversions (independent of CSR)
    cvt_x_kernel<<<(NN * DD / 4 + 255) / 256, 256, 0, stream>>>(x, xb);
    cvt_w_kernel<<<(3 * 128 * 256 + 255) / 256, 256, 0, stream>>>(Wl, Wr, Wcat);

    // CSR build
    hipMemsetAsync(row_ptr, 0, (size_t)(NN + 1) * 4, stream);
    hist_kernel<<<(NE + 255) / 256, 256, 0, stream>>>(dst, row_ptr);
    int nblk = (NN + 1023) / 1024;  // 98
    scan1_kernel<<<nblk, 256, 0, stream>>>(row_ptr, bsum);
    scan2_kernel<<<1, 64, 0, stream>>>(bsum, nblk);
    scan3_kernel<<<(NN + 255) / 256, 256, 0, stream>>>(row_ptr, bsum, cur);
    fill_kernel<<<(NE + 255) / 256, 256, 0, stream>>>(src, dst, cur, csr);

    // 3 SAGE layers (bf16 datapath)
    const unsigned short* hin = xb;
    unsigned short* bufs[2] = {hA, hB};
    for (int l = 0; l < 3; ++l) {
        unsigned short* hout = bufs[l & 1];
        pull_bf16<<<(NN + 3) / 4, 256, 0, stream>>>(hin, row_ptr, csr, aggb);
        sage_mfma<<<(NN + 63) / 64, 256, 0, stream>>>(
            hin, aggb, Wcat + (size_t)l * 128 * 256,
            bl + (size_t)l * 128, br + (size_t)l * 128, row_ptr, hout);
        hin = hout;
    }

    // pooled mean + folded MLP + log_softmax
    hipMemsetAsync(pooled, 0, (size_t)NG * DD * 4, stream);
    hipMemsetAsync(cnt, 0, (size_t)NG * 4, stream);
    pool_bf16<<<256, 256, 0, stream>>>(hin, batch, pooled, cnt);
    mlpfold_kernel<<<8, 256, 0, stream>>>(W1, b1, W2, b2, Wc, bc);
    final_kernel<<<1, 1024, 0, stream>>>(pooled, cnt, Wc, bc, out);
}

// Round 4
// 483.738 us; speedup vs baseline: 1.8888x; 1.3259x over previous
//
#include <hip/hip_runtime.h>
#include <cstdint>
#include <cstddef>

#define NN 100000   // nodes
#define NE 1600000  // edges
#define DD 128      // feature dim
#define NG 64       // graphs
#define NB 782      // buckets of 128 nodes: 782*128 = 100096 >= NN

using bf16x8 = __attribute__((ext_vector_type(8))) short;
using f32x4  = __attribute__((ext_vector_type(4))) float;

__device__ __forceinline__ int clampi(int v, int hi) {
    v = v < 0 ? 0 : v;
    return v >= hi ? hi - 1 : v;
}
__device__ __forceinline__ unsigned short f2bf(float f) {
    unsigned int u = __float_as_uint(f);
    u += 0x7fffu + ((u >> 16) & 1u);   // RNE
    return (unsigned short)(u >> 16);
}
__device__ __forceinline__ float bf2f(unsigned short s) {
    return __uint_as_float(((unsigned int)s) << 16);
}

// ---------------------------------------------------------------------------
// CSR build via bucket sort (all dense writes — no line-amplified scatter)
// ---------------------------------------------------------------------------
// 1) per-block LDS histogram of dst>>7 -> global bucket counts
__global__ __launch_bounds__(256) void bcount_kernel(
    const int* __restrict__ dst, int* __restrict__ bcnt) {
    __shared__ int lcnt[NB];
    for (int i = threadIdx.x; i < NB; i += 256) lcnt[i] = 0;
    __syncthreads();
    int e0 = blockIdx.x * 8000;
    int e1 = e0 + 8000; if (e1 > NE) e1 = NE;
    for (int e = e0 + threadIdx.x; e < e1; e += 256)
        atomicAdd(&lcnt[clampi(dst[e], NN) >> 7], 1);
    __syncthreads();
    for (int i = threadIdx.x; i < NB; i += 256)
        if (lcnt[i]) atomicAdd(&bcnt[i], lcnt[i]);
}

// 2) single-block scan of bucket counts -> bstart[NB+1]; init gcur
__global__ __launch_bounds__(1024) void bscan_kernel(
    const int* __restrict__ bcnt, int* __restrict__ bstart, int* __restrict__ gcur) {
    __shared__ int sh[1024];
    int t = threadIdx.x;
    int own = (t < NB) ? bcnt[t] : 0;
    sh[t] = own;
    __syncthreads();
    for (int d = 1; d < 1024; d <<= 1) {
        int v = (t >= d) ? sh[t - d] : 0;
        __syncthreads();
        sh[t] += v;
        __syncthreads();
    }
    if (t < NB) {
        int excl = sh[t] - own;
        bstart[t] = excl;
        gcur[t] = excl;
    }
    if (t == NB - 1) bstart[NB] = sh[t];
}

// 3) partition (src,dst) pairs into bucket-contiguous staging
__global__ __launch_bounds__(256) void bpart_kernel(
    const int* __restrict__ src, const int* __restrict__ dst,
    int* __restrict__ gcur, uint2* __restrict__ stage) {
    __shared__ int lds[NB];   // pass1: counts; then: running global cursor
    for (int i = threadIdx.x; i < NB; i += 256) lds[i] = 0;
    __syncthreads();
    int e0 = blockIdx.x * 8000;
    int e1 = e0 + 8000; if (e1 > NE) e1 = NE;
    for (int e = e0 + threadIdx.x; e < e1; e += 256)
        atomicAdd(&lds[clampi(dst[e], NN) >> 7], 1);
    __syncthreads();
    for (int i = threadIdx.x; i < NB; i += 256) {
        int c = lds[i];
        if (c) lds[i] = atomicAdd(&gcur[i], c);
    }
    __syncthreads();
    for (int e = e0 + threadIdx.x; e < e1; e += 256) {
        int d = clampi(dst[e], NN);
        int pos = atomicAdd(&lds[d >> 7], 1);
        uint2 p; p.x = (unsigned)clampi(src[e], NN); p.y = (unsigned)d;
        stage[pos] = p;
    }
}

// 4) per-bucket: degree count -> local scan -> row_ptr + dense csr fill
__global__ __launch_bounds__(256) void bfill_kernel(
    const uint2* __restrict__ stage, const int* __restrict__ bstart,
    int* __restrict__ row_ptr, int* __restrict__ csr) {
    __shared__ int scnt[128];
    __shared__ int scur[128];
    const int b = blockIdx.x;
    const int t = threadIdx.x;
    const int s0 = bstart[b], s1 = bstart[b + 1];
    const int n0 = b << 7;
    int nend = NN - n0; if (nend > 128) nend = 128;
    if (t < 128) scnt[t] = 0;
    __syncthreads();
    for (int i = s0 + t; i < s1; i += 256)
        atomicAdd(&scnt[stage[i].y & 127], 1);
    __syncthreads();
    int own = (t < 128) ? scnt[t] : 0;
    for (int d = 1; d < 128; d <<= 1) {
        int v = (t < 128 && t >= d) ? scnt[t - d] : 0;
        __syncthreads();
        if (t < 128) scnt[t] += v;
        __syncthreads();
    }
    if (t < 128) {
        int excl = scnt[t] - own;
        scur[t] = excl;
        if (t < nend) row_ptr[n0 + t] = s0 + excl;
    }
    if (b == NB - 1 && t == 0) row_ptr[NN] = NE;
    __syncthreads();
    for (int i = s0 + t; i < s1; i += 256) {
        uint2 p = stage[i];
        int slot = atomicAdd(&scur[p.y & 127], 1);
        csr[s0 + slot] = (int)p.x;
    }
}

// ---------------------------------------------------------------------------
// Convert kernels: x f32 -> bf16; weights -> concatenated bf16 [l][o][256]
// ---------------------------------------------------------------------------
__global__ void cvt_x_kernel(const float* __restrict__ x, unsigned short* __restrict__ xb) {
    int i = blockIdx.x * 256 + threadIdx.x;     // over NN*DD/4
    if (i >= NN * DD / 4) return;
    const float4 v = ((const float4*)x)[i];
    ushort4 r;
    r.x = f2bf(v.x); r.y = f2bf(v.y); r.z = f2bf(v.z); r.w = f2bf(v.w);
    ((ushort4*)xb)[i] = r;
}

__global__ void cvt_w_kernel(const float* __restrict__ Wl, const float* __restrict__ Wr,
                             unsigned short* __restrict__ Wcat) {
    int t = blockIdx.x * 256 + threadIdx.x;     // 3*128*256
    if (t >= 3 * 128 * 256) return;
    int l = t >> 15;
    int rem = t & 32767;
    int o = rem >> 8, k = rem & 255;
    float v = (k < 128) ? Wl[(size_t)l * 16384 + o * 128 + k]
                        : Wr[(size_t)l * 16384 + o * 128 + (k - 128)];
    Wcat[t] = f2bf(v);
}

// ---------------------------------------------------------------------------
// Pull aggregation (bf16): one wave per dst node; 4 rows per vmem instruction
// (16 lanes x 16B per row). Cross-group reduce via shfl_xor 16/32.
// ---------------------------------------------------------------------------
__global__ __launch_bounds__(256) void pull4_kernel(
    const unsigned short* __restrict__ h, const int* __restrict__ row_ptr,
    const int* __restrict__ csr, unsigned short* __restrict__ agg) {
    int w = threadIdx.x >> 6, lane = threadIdx.x & 63;
    int n = blockIdx.x * 4 + w;
    if (n >= NN) return;
    int g = lane >> 4, c = lane & 15;
    int s0 = row_ptr[n], s1 = row_ptr[n + 1];
    int len = s1 - s0;
    float inv = 1.0f / (float)(len > 0 ? len : 1);
    float acc[8];
#pragma unroll
    for (int i = 0; i < 8; ++i) acc[i] = 0.f;
    for (int j = s0 + g; j < s1; j += 4) {
        int idx = csr[j];
        bf16x8 v = *(const bf16x8*)(h + (size_t)idx * DD + c * 8);
#pragma unroll
        for (int i = 0; i < 8; ++i) acc[i] += bf2f((unsigned short)v[i]);
    }
#pragma unroll
    for (int i = 0; i < 8; ++i) {
        acc[i] += __shfl_xor(acc[i], 16);
        acc[i] += __shfl_xor(acc[i], 32);
    }
    if (g == 0) {
        bf16x8 r;
#pragma unroll
        for (int i = 0; i < 8; ++i) r[i] = (short)f2bf(acc[i] * inv);
        *(bf16x8*)(agg + (size_t)n * DD + c * 8) = r;
    }
}

// ---------------------------------------------------------------------------
// Fused SAGE layer (MFMA bf16):
// out = relu(normalize(h@Wl^T + agg@Wr^T + bl + [deg>0]*br)) -> bf16
// ---------------------------------------------------------------------------
__global__ __launch_bounds__(256) void sage_mfma(
    const unsigned short* __restrict__ h, const unsigned short* __restrict__ agg,
    const unsigned short* __restrict__ Wcat, const float* __restrict__ bl,
    const float* __restrict__ br, const int* __restrict__ row_ptr,
    unsigned short* __restrict__ hOut) {
    __shared__ float ssh[2][64];
    const int tid = threadIdx.x;
    const int l = tid & 63;
    const int w = tid >> 6;
    const int wm = w & 1, wn = w >> 1;
    const int l15 = l & 15, lg = l >> 4;
    const int n0 = blockIdx.x * 64;

    f32x4 acc[2][4];
#pragma unroll
    for (int m = 0; m < 2; ++m)
#pragma unroll
        for (int n = 0; n < 4; ++n) acc[m][n] = (f32x4){0.f, 0.f, 0.f, 0.f};

    int nodeA[2];
#pragma unroll
    for (int m = 0; m < 2; ++m) {
        int r = n0 + wm * 32 + m * 16 + l15;
        nodeA[m] = r < NN ? r : NN - 1;
    }

#pragma unroll
    for (int ks = 0; ks < 8; ++ks) {
        const unsigned short* Abase = (ks < 4) ? h : agg;
        const int kk = (ks & 3) * 32 + lg * 8;
        const int kw = ks * 32 + lg * 8;
        bf16x8 a[2], b[4];
#pragma unroll
        for (int m = 0; m < 2; ++m)
            a[m] = *(const bf16x8*)(Abase + (size_t)nodeA[m] * DD + kk);
#pragma unroll
        for (int n = 0; n < 4; ++n) {
            int o = wn * 64 + n * 16 + l15;
            b[n] = *(const bf16x8*)(Wcat + o * 256 + kw);
        }
#pragma unroll
        for (int m = 0; m < 2; ++m)
#pragma unroll
            for (int n = 0; n < 4; ++n)
                acc[m][n] = __builtin_amdgcn_mfma_f32_16x16x32_bf16(a[m], b[n], acc[m][n], 0, 0, 0);
    }

    float blv[4], brv[4];
#pragma unroll
    for (int n = 0; n < 4; ++n) {
        int o = wn * 64 + n * 16 + l15;
        blv[n] = bl[o]; brv[n] = br[o];
    }

    float outv[2][4][4];
#pragma unroll
    for (int m = 0; m < 2; ++m) {
#pragma unroll
        for (int r = 0; r < 4; ++r) {
            int row_local = wm * 32 + m * 16 + lg * 4 + r;
            int node = n0 + row_local;
            int nd = node < NN ? node : 0;
            float bf = (row_ptr[nd + 1] - row_ptr[nd]) > 0 ? 1.f : 0.f;
            float s = 0.f;
#pragma unroll
            for (int n = 0; n < 4; ++n) {
                float v = acc[m][n][r] + blv[n] + bf * brv[n];
                outv[m][n][r] = v;
                s = fmaf(v, v, s);
            }
            s += __shfl_xor(s, 1); s += __shfl_xor(s, 2);
            s += __shfl_xor(s, 4); s += __shfl_xor(s, 8);
            if (l15 == 0) ssh[wn][row_local] = s;
        }
    }
    __syncthreads();
#pragma unroll
    for (int m = 0; m < 2; ++m) {
#pragma unroll
        for (int r = 0; r < 4; ++r) {
            int row_local = wm * 32 + m * 16 + lg * 4 + r;
            int node = n0 + row_local;
            float tot = ssh[0][row_local] + ssh[1][row_local];
            float inv = 1.0f / fmaxf(sqrtf(tot), 1e-12f);
            if (node < NN) {
#pragma unroll
                for (int n = 0; n < 4; ++n) {
                    int o = wn * 64 + n * 16 + l15;
                    float v = fmaxf(outv[m][n][r], 0.f) * inv;
                    hOut[(size_t)node * DD + o] = f2bf(v);
                }
            }
        }
    }
}

// ---------------------------------------------------------------------------
// Pool: segment-mean of h3 (bf16) by sorted batch -> pooled[64][128], cnt[64]
// ---------------------------------------------------------------------------
__global__ __launch_bounds__(256) void pool_bf16(
    const unsigned short* __restrict__ h, const int* __restrict__ batch,
    float* __restrict__ pooled, float* __restrict__ cnt) {
    int hw = (blockIdx.x * blockDim.x + threadIdx.x) >> 5;
    int lane = threadIdx.x & 31;
    int total_hw = (gridDim.x * blockDim.x) >> 5;
    int chunk = (NN + total_hw - 1) / total_hw;
    int nbeg = hw * chunk;
    int nend = nbeg + chunk; if (nend > NN) nend = NN;
    if (nbeg >= nend) return;
    float ax = 0.f, ay = 0.f, az = 0.f, aw = 0.f;
    int curg = clampi(batch[nbeg], NG);
    int run = 0;
    for (int n = nbeg; n < nend; ++n) {
        int g = clampi(batch[n], NG);
        if (g != curg) {
            atomicAdd(&pooled[curg * DD + lane * 4 + 0], ax);
            atomicAdd(&pooled[curg * DD + lane * 4 + 1], ay);
            atomicAdd(&pooled[curg * DD + lane * 4 + 2], az);
            atomicAdd(&pooled[curg * DD + lane * 4 + 3], aw);
            if (lane == 0) atomicAdd(&cnt[curg], (float)run);
            ax = ay = az = aw = 0.f; run = 0; curg = g;
        }
        const ushort4 v = *(const ushort4*)(h + (size_t)n * DD + lane * 4);
        ax += bf2f(v.x); ay += bf2f(v.y); az += bf2f(v.z); aw += bf2f(v.w);
        ++run;
    }
    atomicAdd(&pooled[curg * DD + lane * 4 + 0], ax);
    atomicAdd(&pooled[curg * DD + lane * 4 + 1], ay);
    atomicAdd(&pooled[curg * DD + lane * 4 + 2], az);
    atomicAdd(&pooled[curg * DD + lane * 4 + 3], aw);
    if (lane == 0) atomicAdd(&cnt[curg], (float)run);
}

// ---------------------------------------------------------------------------
// Fold MLP: Wc = W2 @ W1 (16x128), bc = W2 @ b1 + b2
// ---------------------------------------------------------------------------
__global__ void mlpfold_kernel(const float* __restrict__ W1, const float* __restrict__ b1,
                               const float* __restrict__ W2, const float* __restrict__ b2,
                               float* __restrict__ Wc, float* __restrict__ bc) {
    int t = blockIdx.x * 256 + threadIdx.x;
    if (t >= 16 * 128) return;
    int o = t >> 7, k = t & 127;
    float s = 0.f;
    for (int j = 0; j < 128; ++j) s = fmaf(W2[o * 128 + j], W1[j * 128 + k], s);
    Wc[o * 128 + k] = s;
    if (k == 0) {
        float sb = 0.f;
        for (int j = 0; j < 128; ++j) sb = fmaf(W2[o * 128 + j], b1[j], sb);
        bc[o] = sb + b2[o];
    }
}

// ---------------------------------------------------------------------------
// Final: mean -> micro GEMM [64][128]@[128][16] -> log_softmax -> d_out
// ---------------------------------------------------------------------------
__global__ void final_kernel(const float* __restrict__ pooled, const float* __restrict__ cnt,
                             const float* __restrict__ Wc, const float* __restrict__ bc,
                             float* __restrict__ out) {
    int t = threadIdx.x;          // 1024 = 64 graphs x 16 outs
    int g = t >> 4, o = t & 15;
    float invc = 1.0f / fmaxf(cnt[g], 1.0f);
    float z = bc[o];
    for (int k = 0; k < 128; ++k) z = fmaf(pooled[g * DD + k] * invc, Wc[o * 128 + k], z);
    float m = z;
    m = fmaxf(m, __shfl_xor(m, 1)); m = fmaxf(m, __shfl_xor(m, 2));
    m = fmaxf(m, __shfl_xor(m, 4)); m = fmaxf(m, __shfl_xor(m, 8));
    float e = expf(z - m);
    float s = e;
    s += __shfl_xor(s, 1); s += __shfl_xor(s, 2);
    s += __shfl_xor(s, 4); s += __shfl_xor(s, 8);
    out[g * 16 + o] = z - m - logf(s);
}

__global__ void zero_out_kernel(float* __restrict__ out, int n) {
    int i = blockIdx.x * 256 + threadIdx.x;
    if (i < n) out[i] = 0.f;
}

// ---------------------------------------------------------------------------
extern "C" void kernel_launch(void* const* d_in, const int* in_sizes, int n_in,
                              void* d_out, int out_size, void* d_ws, size_t ws_size,
                              hipStream_t stream) {
    const float* x  = (const float*)d_in[0];
    const int*   ei = (const int*)d_in[1];
    const int* batch = (const int*)d_in[2];
    const float* Wl = (const float*)d_in[3];
    const float* bl = (const float*)d_in[4];
    const float* Wr = (const float*)d_in[5];
    const float* br = (const float*)d_in[6];
    const float* W1 = (const float*)d_in[7];
    const float* b1 = (const float*)d_in[8];
    const float* W2 = (const float*)d_in[9];
    const float* b2 = (const float*)d_in[10];
    float* out = (float*)d_out;

    const int* src = ei;          // edge_index[0]
    const int* dst = ei + NE;     // edge_index[1]

    char* ws = (char*)d_ws;
    size_t off = 0;
    auto alloc = [&](size_t bytes) -> void* {
        void* p = ws + off; off += (bytes + 255) & ~(size_t)255; return p;
    };
    unsigned short* xb   = (unsigned short*)alloc((size_t)NN * DD * 2);
    unsigned short* hA   = (unsigned short*)alloc((size_t)NN * DD * 2);
    unsigned short* hB   = (unsigned short*)alloc((size_t)NN * DD * 2);
    unsigned short* aggb = (unsigned short*)alloc((size_t)NN * DD * 2);
    unsigned short* Wcat = (unsigned short*)alloc((size_t)3 * 128 * 256 * 2);
    int* row_ptr  = (int*)alloc((size_t)(NN + 1) * 4);
    int* csr      = (int*)alloc((size_t)NE * 4);
    uint2* stage  = (uint2*)alloc((size_t)NE * 8);
    int* bcnt     = (int*)alloc((size_t)NB * 4);
    int* bstart   = (int*)alloc((size_t)(NB + 1) * 4);
    int* gcur     = (int*)alloc((size_t)NB * 4);
    float* pooled = (float*)alloc(NG * DD * 4);
    float* cnt    = (float*)alloc(NG * 4);
    float* Wc     = (float*)alloc(16 * DD * 4);
    float* bc     = (float*)alloc(16 * 4);

    if (off > ws_size) {
        zero_out_kernel<<<(out_size + 255) / 256, 256, 0, stream>>>(out, out_size);
        return;
    }

    // conversions (independent of CSR)
    cvt_x_kernel<<<(NN * DD / 4 + 255) / 256, 256, 0, stream>>>(x, xb);
    cvt_w_kernel<<<(3 * 128 * 256 + 255) / 256, 256, 0, stream>>>(Wl, Wr, Wcat);

    // CSR build via bucket sort (dense writes)
    hipMemsetAsync(bcnt, 0, (size_t)NB * 4, stream);
    const int npb = (NE + 7999) / 8000;   // 200 partition/count blocks
    bcount_kernel<<<npb, 256, 0, stream>>>(dst, bcnt);
    bscan_kernel<<<1, 1024, 0, stream>>>(bcnt, bstart, gcur);
    bpart_kernel<<<npb, 256, 0, stream>>>(src, dst, gcur, stage);
    bfill_kernel<<<NB, 256, 0, stream>>>(stage, bstart, row_ptr, csr);

    // 3 SAGE layers (bf16 datapath)
    const unsigned short* hin = xb;
    unsigned short* bufs[2] = {hA, hB};
    for (int l = 0; l < 3; ++l) {
        unsigned short* hout = bufs[l & 1];
        pull4_kernel<<<(NN + 3) / 4, 256, 0, stream>>>(hin, row_ptr, csr, aggb);
        sage_mfma<<<(NN + 63) / 64, 256, 0, stream>>>(
            hin, aggb, Wcat + (size_t)l * 128 * 256,
            bl + (size_t)l * 128, br + (size_t)l * 128, row_ptr, hout);
        hin = hout;
    }

    // pooled mean + folded MLP + log_softmax
    hipMemsetAsync(pooled, 0, (size_t)NG * DD * 4, stream);
    hipMemsetAsync(cnt, 0, (size_t)NG * 4, stream);
    pool_bf16<<<256, 256, 0, stream>>>(hin, batch, pooled, cnt);
    mlpfold_kernel<<<8, 256, 0, stream>>>(W1, b1, W2, b2, Wc, bc);
    final_kernel<<<1, 1024, 0, stream>>>(pooled, cnt, Wc, bc, out);
}